// Round 4
// baseline (675.018 us; speedup 1.0000x reference)
//
#include <hip/hip_runtime.h>

// MultiHeadedAttention: B=2, S=2048, D=1024, H=16, DH=64. fp32 in/out.
// R4: occupancy round.
//  - attn: 2048 blocks; block = same (b,h,q-tile32), 4 waves = 2 q-sub(16) x
//    2 k-splits(1024 keys); LDS combine of k-split partials (valid because
//    no-max softmax => merge is a pure add). 24 waves/CU (was 8).
//  - QKV projections fused into ONE GEMM dispatch (N=3072), tile 64x128,
//    wave 32x64 -> 1536 blocks = 24 waves/CU (was 1 wave/SIMD each!).
//  - final GEMM tile 64x128 -> 512 blocks = 8 waves/CU.
#define B_ 2
#define S_ 2048
#define D_ 1024
#define H_ 16
#define DH_ 64

typedef float f32x4 __attribute__((ext_vector_type(4)));
typedef short s16x8 __attribute__((ext_vector_type(8)));
typedef short s16x4 __attribute__((ext_vector_type(4)));
typedef __bf16 bf16x8 __attribute__((ext_vector_type(8)));
typedef unsigned int uint;

// ---- MFMA wrapper: tolerate either builtin signature (short8 or bf16x8) ----
template <typename T>
static __device__ auto mfma_sel(T a, T b, f32x4 c, int)
    -> decltype(__builtin_amdgcn_mfma_f32_16x16x32_bf16(a, b, c, 0, 0, 0)) {
  return __builtin_amdgcn_mfma_f32_16x16x32_bf16(a, b, c, 0, 0, 0);
}
template <typename T>
static __device__ f32x4 mfma_sel(T a, T b, f32x4 c, long) {
  return __builtin_amdgcn_mfma_f32_16x16x32_bf16(
      __builtin_bit_cast(bf16x8, a), __builtin_bit_cast(bf16x8, b), c, 0, 0, 0);
}
static __device__ __forceinline__ f32x4 mfma_bf16(s16x8 a, s16x8 b, f32x4 c) {
  return mfma_sel(a, b, c, 0);
}

static __device__ __forceinline__ short f2bf(float f) {
  unsigned u = __float_as_uint(f);
  u += 0x7fffu + ((u >> 16) & 1u);
  return (short)(u >> 16);
}

template <bool F32>
static __device__ __forceinline__ s16x8 ldfrag(const void* p, size_t off) {
  if constexpr (F32) {
    const float* f = (const float*)p + off;
    f32x4 a = *(const f32x4*)f;
    f32x4 b = *(const f32x4*)(f + 4);
    s16x8 r;
    r[0] = f2bf(a[0]); r[1] = f2bf(a[1]); r[2] = f2bf(a[2]); r[3] = f2bf(a[3]);
    r[4] = f2bf(b[0]); r[5] = f2bf(b[1]); r[6] = f2bf(b[2]); r[7] = f2bf(b[3]);
    return r;
  } else {
    return *(const s16x8*)((const short*)p + off);
  }
}

// ---- mask dtype probe: 0 = byte-bool, 1 = int32 0/1, 2 = fp32 0.0/1.0 ----
__global__ void detect_mask_kernel(const uint* __restrict__ m,
                                   int* __restrict__ flag) {
  int lane = threadIdx.x;
  bool gt1 = false, notf = false;
  for (int i = 0; i < 16; ++i) {
    uint v = m[lane * 16 + i];
    if (v > 1u) gt1 = true;
    if (v != 0u && v != 0x3F800000u) notf = true;
  }
  unsigned long long b1 = __ballot(gt1);
  unsigned long long b2 = __ballot(notf);
  if (lane == 0) {
    int f;
    if (b1 == 0ull) f = 1;
    else if (b2 == 0ull) f = 2;
    else f = 0;
    *flag = f;
  }
}

// ---- mask -> bitmask. bmT[b][kt][q] bit i = (mask[b][q][kt*32+i] != 0) ----
__global__ __launch_bounds__(256) void build_bitmask_kernel(
    const void* __restrict__ mask, const int* __restrict__ flag,
    uint* __restrict__ bmT) {
  int w = blockIdx.x * 256 + threadIdx.x;
  int b = w >> 17;
  int rem = w & 131071;
  int q = rem >> 6;
  int kt = rem & 63;
  int mty = *flag;
  uint bits = 0;
  if (mty == 0) {
    const uint* p = (const uint*)((const unsigned char*)mask +
                                  ((size_t)b * S_ + q) * S_ + (size_t)kt * 32);
#pragma unroll
    for (int i = 0; i < 8; ++i) {
      uint v = p[i];
#pragma unroll
      for (int j = 0; j < 4; ++j)
        if ((v >> (8 * j)) & 0xffu) bits |= 1u << (i * 4 + j);
    }
  } else {
    const uint* p = (const uint*)mask + ((size_t)b * S_ + q) * S_ + kt * 32;
#pragma unroll
    for (int i = 0; i < 32; ++i)
      if (p[i]) bits |= 1u << i;
  }
  bmT[((size_t)b * (S_ / 32) + kt) * S_ + q] = bits;
}

// ---- fp32 -> bf16 bulk convert: query (2048 blk) + Wq/Wk/Wv (512 blk each) ----
__global__ __launch_bounds__(256) void convert_kernel(
    const float* __restrict__ q, const float* __restrict__ wq,
    const float* __restrict__ wk, const float* __restrict__ wv,
    short* __restrict__ qbf, short* __restrict__ wqkv) {
  int bid = blockIdx.x;
  const float* src;
  short* dst;
  size_t base;
  if (bid < 2048) { src = q;  dst = qbf;  base = (size_t)bid * 2048; }
  else if (bid < 2560) { src = wq; dst = wqkv;              base = (size_t)(bid - 2048) * 2048; }
  else if (bid < 3072) { src = wk; dst = wqkv + 1048576;    base = (size_t)(bid - 2560) * 2048; }
  else { src = wv; dst = wqkv + 2097152; base = (size_t)(bid - 3072) * 2048; }
  size_t i = base + (size_t)threadIdx.x * 8;
  f32x4 a = *(const f32x4*)(src + i);
  f32x4 b = *(const f32x4*)(src + i + 4);
  s16x8 r;
  r[0] = f2bf(a[0]); r[1] = f2bf(a[1]); r[2] = f2bf(a[2]); r[3] = f2bf(a[3]);
  r[4] = f2bf(b[0]); r[5] = f2bf(b[1]); r[6] = f2bf(b[2]); r[7] = f2bf(b[3]);
  *(s16x8*)(dst + i) = r;
}

// ---- fused QKV GEMM: C[4096,3072] = qbf @ wqkv^T, routed epilogue ----
// n in [0,1024): q -> q_ws (scale 1/8);  [1024,2048): k -> k_ws;
// [2048,3072): v -> vt_ws transposed.
__global__ __launch_bounds__(256, 6) void gemm_qkv_kernel(
    const short* __restrict__ A, const short* __restrict__ Bt,
    const float* __restrict__ bq, const float* __restrict__ bk,
    const float* __restrict__ bv, short* __restrict__ q_ws,
    short* __restrict__ k_ws, short* __restrict__ vt_ws) {
  const int tid = threadIdx.x;
  const int lane = tid & 63;
  const int wave = tid >> 6;
  const int l16 = lane & 15;
  const int quad = lane >> 4;
  const int m0 = blockIdx.x * 64 + (wave >> 1) * 32;
  const int n0 = blockIdx.y * 128 + (wave & 1) * 64;

  f32x4 acc[2][4];
#pragma unroll
  for (int i = 0; i < 2; ++i)
#pragma unroll
    for (int j = 0; j < 4; ++j) acc[i][j] = (f32x4){0.f, 0.f, 0.f, 0.f};

  for (int k0 = 0; k0 < 1024; k0 += 32) {
    s16x8 a[2], b[4];
#pragma unroll
    for (int i = 0; i < 2; ++i)
      a[i] = *(const s16x8*)(A + (size_t)(m0 + i * 16 + l16) * 1024 + k0 + quad * 8);
#pragma unroll
    for (int j = 0; j < 4; ++j)
      b[j] = *(const s16x8*)(Bt + (size_t)(n0 + j * 16 + l16) * 1024 + k0 + quad * 8);
#pragma unroll
    for (int i = 0; i < 2; ++i)
#pragma unroll
      for (int j = 0; j < 4; ++j) acc[i][j] = mfma_bf16(a[i], b[j], acc[i][j]);
  }

#pragma unroll
  for (int i = 0; i < 2; ++i) {
#pragma unroll
    for (int j = 0; j < 4; ++j) {
#pragma unroll
      for (int r = 0; r < 4; ++r) {
        int m = m0 + i * 16 + quad * 4 + r;
        int n = n0 + j * 16 + l16;
        int seg = n >> 10, nl = n & 1023;
        float bias = (seg == 0) ? bq[nl] : ((seg == 1) ? bk[nl] : bv[nl]);
        float v = acc[i][j][r] + bias;
        if (seg == 0) v *= 0.125f;
        int bb = m >> 11, s = m & (S_ - 1);
        int hh = nl >> 6, dh = nl & 63;
        if (seg < 2) {
          short* dst = (seg == 0) ? q_ws : k_ws;
          dst[((size_t)(bb * H_ + hh) * S_ + s) * DH_ + dh] = f2bf(v);
        } else {
          vt_ws[((size_t)(bb * H_ + hh) * DH_ + dh) * S_ + s] = f2bf(v);
        }
      }
    }
  }
}

// ---- attention: block = (b,h,qt32); 4 waves = 2 q-sub(16) x 2 k-split ----
__global__ __launch_bounds__(256, 6) void attn_kernel(
    const short* __restrict__ Q, const short* __restrict__ Km,
    const short* __restrict__ Vt, const uint* __restrict__ bmT,
    short* __restrict__ ctx_out) {
  __shared__ float lctx[2][16][64];
  __shared__ float lls[2][16];
  const int tid = threadIdx.x;
  const int lane = tid & 63;
  const int wave = tid >> 6;
  const int l16 = lane & 15;
  const int quad = lane >> 4;
  const int qs = wave & 1;
  const int ks = wave >> 1;
  const int bid = blockIdx.x;
  const int b = bid >> 10;
  const int h = (bid >> 6) & 15;
  const int qt = bid & 63;
  const int qbase = qt * 32 + qs * 16;

  const short* Qh = Q + (size_t)(b * H_ + h) * S_ * DH_;
  const short* Kh = Km + (size_t)(b * H_ + h) * S_ * DH_;
  const short* Vh = Vt + (size_t)(b * H_ + h) * DH_ * S_;
  const uint* bmb = bmT + (size_t)b * (S_ / 32) * S_;

  // Q B-fragments (16 q-rows): B[n=l16][k=quad*8+j]
  s16x8 qf[2];
#pragma unroll
  for (int kf = 0; kf < 2; ++kf)
    qf[kf] = *(const s16x8*)(Qh + (size_t)(qbase + l16) * DH_ + kf * 32 + quad * 8);

  f32x4 ctx[4];
#pragma unroll
  for (int nb = 0; nb < 4; ++nb) ctx[nb] = (f32x4){0.f, 0.f, 0.f, 0.f};
  float ls = 0.f;

  for (int kt = 0; kt < 32; ++kt) {
    const int k0 = ks * 1024 + kt * 32;
    // hoist ALL loads of this iteration for memory-level parallelism
    s16x8 ka[2][2];
#pragma unroll
    for (int kb = 0; kb < 2; ++kb)
#pragma unroll
      for (int kf = 0; kf < 2; ++kf)
        ka[kb][kf] = *(const s16x8*)(Kh + (size_t)(k0 + kb * 16 + l16) * DH_ +
                                     kf * 32 + quad * 8);
    uint w = bmb[(size_t)(k0 >> 5) * S_ + qbase + l16];
    s16x8 vb[4];
#pragma unroll
    for (int nb = 0; nb < 4; ++nb) {
      const short* vrow = Vh + (size_t)(nb * 16 + l16) * S_ + k0 + quad * 4;
      s16x4 lo = *(const s16x4*)(vrow);
      s16x4 hi = *(const s16x4*)(vrow + 16);
      vb[nb] = __builtin_shufflevector(lo, hi, 0, 1, 2, 3, 4, 5, 6, 7);
    }

    // scores^T: C row = key(quad*4+r), col = q(l16)
    f32x4 sc[2];
#pragma unroll
    for (int kb = 0; kb < 2; ++kb) {
      f32x4 t = mfma_bf16(ka[kb][0], qf[0], (f32x4){0.f, 0.f, 0.f, 0.f});
      sc[kb] = mfma_bf16(ka[kb][1], qf[1], t);
    }

    // exp + mask + pack to PV A-operand (k_phys = (j>>2)*16 + quad*4 + (j&3))
    s16x8 pa;
    float sum = 0.f;
#pragma unroll
    for (int kb = 0; kb < 2; ++kb)
#pragma unroll
      for (int r = 0; r < 4; ++r) {
        int bit = (w >> (kb * 16 + quad * 4 + r)) & 1;
        float p = bit ? 0.f : __expf(sc[kb][r]);
        sum += p;
        pa[kb * 4 + r] = f2bf(p);
      }
    ls += sum;

#pragma unroll
    for (int nb = 0; nb < 4; ++nb) ctx[nb] = mfma_bf16(pa, vb[nb], ctx[nb]);
  }

  // reduce l over the 4 quads: every lane ends with row l16's total
  ls += __shfl_xor(ls, 16);
  ls += __shfl_xor(ls, 32);

  if (ks == 1) {
#pragma unroll
    for (int nb = 0; nb < 4; ++nb)
#pragma unroll
      for (int r = 0; r < 4; ++r)
        lctx[qs][quad * 4 + r][nb * 16 + l16] = ctx[nb][r];
    if (lane < 16) lls[qs][l16] = ls;
  }
  __syncthreads();
  if (ks == 0) {
    float lsum = ls + lls[qs][l16];
#pragma unroll
    for (int nb = 0; nb < 4; ++nb)
#pragma unroll
      for (int r = 0; r < 4; ++r)
        ctx[nb][r] += lctx[qs][quad * 4 + r][nb * 16 + l16];
#pragma unroll
    for (int r = 0; r < 4; ++r) {
      float lr = __shfl(lsum, quad * 4 + r);
      float inv = 1.f / lr;
      int srow = qbase + quad * 4 + r;
#pragma unroll
      for (int nb = 0; nb < 4; ++nb) {
        int col = h * DH_ + nb * 16 + l16;
        ctx_out[(size_t)(b * S_ + srow) * D_ + col] = f2bf(ctx[nb][r] * inv);
      }
    }
  }
}

// ---- final GEMM: out[4096,1024] fp32 = ctx_bf16 @ Wo^T + bo ----
__global__ __launch_bounds__(256) void gemm_final_kernel(
    const short* __restrict__ A, const float* __restrict__ Bt,
    const float* __restrict__ bias, float* __restrict__ out) {
  const int tid = threadIdx.x;
  const int lane = tid & 63;
  const int wave = tid >> 6;
  const int l16 = lane & 15;
  const int quad = lane >> 4;
  const int m0 = blockIdx.x * 64 + (wave >> 1) * 32;
  const int n0 = blockIdx.y * 128 + (wave & 1) * 64;

  f32x4 acc[2][4];
#pragma unroll
  for (int i = 0; i < 2; ++i)
#pragma unroll
    for (int j = 0; j < 4; ++j) acc[i][j] = (f32x4){0.f, 0.f, 0.f, 0.f};

  for (int k0 = 0; k0 < 1024; k0 += 32) {
    s16x8 a[2], b[4];
#pragma unroll
    for (int i = 0; i < 2; ++i)
      a[i] = *(const s16x8*)(A + (size_t)(m0 + i * 16 + l16) * 1024 + k0 + quad * 8);
#pragma unroll
    for (int j = 0; j < 4; ++j)
      b[j] = ldfrag<true>(Bt, (size_t)(n0 + j * 16 + l16) * 1024 + k0 + quad * 8);
#pragma unroll
    for (int i = 0; i < 2; ++i)
#pragma unroll
      for (int j = 0; j < 4; ++j) acc[i][j] = mfma_bf16(a[i], b[j], acc[i][j]);
  }

#pragma unroll
  for (int i = 0; i < 2; ++i)
#pragma unroll
    for (int j = 0; j < 4; ++j)
#pragma unroll
      for (int r = 0; r < 4; ++r) {
        int m = m0 + i * 16 + quad * 4 + r;
        int n = n0 + j * 16 + l16;
        out[(size_t)m * 1024 + n] = acc[i][j][r] + bias[n];
      }
}

extern "C" void kernel_launch(void* const* d_in, const int* in_sizes, int n_in,
                              void* d_out, int out_size, void* d_ws,
                              size_t ws_size, hipStream_t stream) {
  const float* query = (const float*)d_in[0];
  const void* mask = d_in[1];
  const float* Wq = (const float*)d_in[2];
  const float* bq = (const float*)d_in[3];
  const float* Wk = (const float*)d_in[4];
  const float* bk = (const float*)d_in[5];
  const float* Wv = (const float*)d_in[6];
  const float* bv = (const float*)d_in[7];
  const float* Wo = (const float*)d_in[8];
  const float* bo = (const float*)d_in[9];

  const size_t NE = (size_t)B_ * S_ * D_;  // 4194304
  short* ws_s = (short*)d_ws;
  short* q_ws = ws_s;             // [B,H,S,DH] bf16
  short* k_ws = ws_s + NE;        // [B,H,S,DH] bf16
  short* vt_ws = ws_s + 2 * NE;   // [B,H,DH,S] bf16
  short* wqkv_bf = ws_s + 3 * NE; // [3072,1024] bf16 (dead after QKV GEMM)
  short* ctx_ws = ws_s + 3 * NE;  // [B,S,D] bf16 -- aliases wqkv (safe)
  // scratch inside d_out (dead before the final GEMM runs):
  short* qbf = (short*)d_out;     // 8 MB query bf16
  uint* bmT = (uint*)(qbf + NE);  // 1 MB bitmask
  int* flag = (int*)(bmT + (size_t)B_ * (S_ / 32) * S_);

  detect_mask_kernel<<<1, 64, 0, stream>>>((const uint*)mask, flag);
  build_bitmask_kernel<<<1024, 256, 0, stream>>>(mask, flag, bmT);
  convert_kernel<<<3584, 256, 0, stream>>>(query, Wq, Wk, Wv, qbf, wqkv_bf);

  gemm_qkv_kernel<<<dim3(64, 24), 256, 0, stream>>>(qbf, wqkv_bf, bq, bk, bv,
                                                    q_ws, k_ws, vt_ws);

  attn_kernel<<<2048, 256, 0, stream>>>(q_ws, k_ws, vt_ws, bmT, ctx_ws);

  gemm_final_kernel<<<dim3(64, 8), 256, 0, stream>>>(ctx_ws, Wo, bo,
                                                     (float*)d_out);
}